// Round 11
// baseline (758.035 us; speedup 1.0000x reference)
//
#include <hip/hip_runtime.h>

#define NTOK 65536
#define DIMD 256
#define VOC  1024
#define NLEV 4
#define TAUP 0.052f   // screened top-2 gap below this -> exact resolution

typedef __attribute__((ext_vector_type(8))) _Float16 f16x8;
typedef __attribute__((ext_vector_type(4))) float f32x4;

// ---------------------------------------------------------------------------
// ws layout:
//   [0]        double loss_acc
//   [8]        int    cnts[8]              (per level: [2l]=full, [2l+1]=pair)
//   [64]       float  wnorm[NLEV][VOC]     (16 KB)
//   [16448]    u16    idx[NLEV][NTOK]      (512 KB)
//   [540736]   int    flist[NTOK]          (256 KB)
//   [802880]   int2   plist[NTOK]          (512 KB)
//   [1327168]  uint4  wimg[NLEV*512*64]    (2 MB)  f16 W in FRAGMENT order
// residual fp32 lives in d_out[1:] until k_finale rewrites it.
// wimg fragment f = p*16 + dc*2 + n; lane l = W[p*32+n*16+(l&15)][dc*32+(l>>4)*8..+8]
// ---------------------------------------------------------------------------

__device__ __forceinline__ uint4 cvt8_f16_u(const float4 x0, const float4 x1) {
    union { f16x8 h; uint4 u; } r;
    r.h[0] = (_Float16)x0.x; r.h[1] = (_Float16)x0.y;
    r.h[2] = (_Float16)x0.z; r.h[3] = (_Float16)x0.w;
    r.h[4] = (_Float16)x1.x; r.h[5] = (_Float16)x1.y;
    r.h[6] = (_Float16)x1.z; r.h[7] = (_Float16)x1.w;
    return r.u;
}

__device__ __forceinline__ f16x8 cvt8_f16(const float4 x0, const float4 x1) {
    union { f16x8 h; uint4 u; } r;
    r.h[0] = (_Float16)x0.x; r.h[1] = (_Float16)x0.y;
    r.h[2] = (_Float16)x0.z; r.h[3] = (_Float16)x0.w;
    r.h[4] = (_Float16)x1.x; r.h[5] = (_Float16)x1.y;
    r.h[6] = (_Float16)x1.z; r.h[7] = (_Float16)x1.w;
    return r.h;
}

__device__ __forceinline__ f16x8 u2h(uint4 u) {
    union { uint4 u; f16x8 h; } r; r.u = u; return r.h;
}

// monotone float->u32 (ascending), and inverse
__device__ __forceinline__ unsigned f2u(float s) {
    const int b = __float_as_int(s);
    return (unsigned)(b ^ ((b >> 31) | 0x80000000));
}
__device__ __forceinline__ float u2f(unsigned u) {
    const unsigned m = (u & 0x80000000u) ? 0x80000000u : 0xFFFFFFFFu;
    return __uint_as_float(u ^ m);
}
__device__ __forceinline__ unsigned med3u(unsigned a, unsigned b, unsigned c) {
    unsigned d;
    asm("v_med3_u32 %0, %1, %2, %3" : "=v"(d) : "v"(a), "v"(b), "v"(c));
    return d;
}

// merge two ascending u32 triples with (value, idx) lexicographic order
__device__ __forceinline__ void merge3u(unsigned& a1, unsigned& a2, unsigned& a3,
                                        int& ai1, int& ai2,
                                        unsigned o1, unsigned o2, unsigned o3,
                                        int oi1, int oi2)
{
    const bool sw = (o1 < a1) || (o1 == a1 && oi1 < ai1);
    const unsigned b1 = sw ? o1 : a1; const int bi1 = sw ? oi1 : ai1;
    const unsigned c1 = sw ? a1 : o1; const int ci1 = sw ? ai1 : oi1;
    const unsigned b2 = sw ? o2 : a2; const int bi2 = sw ? oi2 : ai2;
    const unsigned c2 = sw ? a2 : o2;
    const unsigned b3 = sw ? o3 : a3;
    a1 = b1; ai1 = bi1;
    if (c1 < b2 || (c1 == b2 && ci1 < bi2)) {
        a2 = c1; ai2 = ci1; a3 = min(b2, c2);
    } else {
        a2 = b2; ai2 = bi2; a3 = min(b3, c1);
    }
}

// ---------- pre-convert W into fragment-ordered f16 image -------------------
__global__ void k_wsplit(const float* __restrict__ emb, uint4* __restrict__ wimg,
                         int* cnts)
{
    if (blockIdx.x == 0 && threadIdx.x < 8) cnts[threadIdx.x] = 0;
    const int l = blockIdx.x >> 5, p = blockIdx.x & 31;   // grid = NLEV*32
    const int lane = threadIdx.x & 63, q = threadIdx.x >> 6;
    const int lr = lane & 15, lg = lane >> 4;
    #pragma unroll
    for (int i = 0; i < 4; ++i) {
        const int f  = q * 4 + i;          // fragment 0..15 within p-tile
        const int dc = f >> 1, n = f & 1;
        const int code = p * 32 + n * 16 + lr;
        const float* src = emb + ((size_t)(l * VOC + code)) * DIMD + dc * 32 + lg * 8;
        const float4 x0 = *reinterpret_cast<const float4*>(src);
        const float4 x1 = *reinterpret_cast<const float4*>(src + 4);
        wimg[(((size_t)(l * 32 + p)) * 16 + f) * 64 + lane] = cvt8_f16_u(x0, x1);
    }
}

// ------------------- numpy pairwise sum-of-squares -------------------------
__device__ __forceinline__ float np_pairnorm_row(const float* row, int j)
{
#pragma clang fp contract(off)
    const int half = j >> 3;
    const int jj   = j & 7;
    const float* a = row + half * 128 + jj;
    float r = a[0] * a[0];
    #pragma unroll
    for (int i = 1; i < 16; ++i) {
        const float x  = a[8 * i];
        const float sq = x * x;
        r = r + sq;
    }
    r = r + __shfl_xor(r, 1);
    r = r + __shfl_xor(r, 2);
    r = r + __shfl_xor(r, 4);
    r = r + __shfl_xor(r, 8);
    return r;
}

__global__ void k_pairnorm(const float* src, float* __restrict__ dst,
                           int nrows, double* loss_acc)
{
    if (loss_acc && blockIdx.x == 0 && threadIdx.x == 0) *loss_acc = 0.0;
    const int gtid  = blockIdx.x * blockDim.x + threadIdx.x;
    const int gwave = gtid >> 6;
    const int lane  = threadIdx.x & 63;
    const int nwave = (gridDim.x * blockDim.x) >> 6;
    const int sub   = lane >> 4;
    const int j     = lane & 15;
    for (int r4 = gwave; r4 * 4 < nrows; r4 += nwave) {
        const int row = r4 * 4 + sub;
        const float v = np_pairnorm_row(src + (size_t)row * DIMD, j);
        if (j == 0) dst[row] = v;
    }
}

#define MFMA16(A, B, C) __builtin_amdgcn_mfma_f32_16x16x32_f16((A), (B), (C), 0, 0, 0)

// ------------- screen: 16 tokens/wave, 64/block, 4 blocks/CU ----------------
// Named-reg A + depth-4 pair B prefetch, block-uniform B stream, no LDS.
template<int UPD>
__global__ __launch_bounds__(256, 4)
void k_screen(const float* rin, const float* __restrict__ qemb_prev,
              const unsigned short* __restrict__ idx_prev, float* res_out,
              const uint4* __restrict__ wimg_l, const float* __restrict__ wnorml,
              unsigned short* __restrict__ idxl, int2* __restrict__ plist,
              int* __restrict__ flist, int* cnts_l, double* loss_acc)
{
    const int lane = threadIdx.x & 63, w = threadIdx.x >> 6;
    const int lr = lane & 15, lg = lane >> 4;
    const int wbase = blockIdx.x * 64 + w * 16;
    const int p0 = blockIdx.x & 31;           // block-uniform stream start

    const uint4* ib = wimg_l + lane;   // per-lane fragment base

    // ---- issue B prologue loads first (pairs 0..3 of this block's stream) ----
    uint4 sb0a, sb0b, sb1a, sb1b, sb2a, sb2b, sb3a, sb3b;
    {
        const size_t fb = (size_t)p0 * 16;
        sb0a = ib[(fb + 0) * 64]; sb0b = ib[(fb + 1) * 64];
        sb1a = ib[(fb + 2) * 64]; sb1b = ib[(fb + 3) * 64];
        sb2a = ib[(fb + 4) * 64]; sb2b = ib[(fb + 5) * 64];
        sb3a = ib[(fb + 6) * 64]; sb3b = ib[(fb + 7) * 64];
    }

    // ---- A prologue: named fragments (+ fused residual update) ----
    f16x8 af_0, af_1, af_2, af_3, af_4, af_5, af_6, af_7;
    float lsum = 0.0f;
    const float* rrow = rin + (size_t)(wbase + lr) * DIMD;
    const float* qrow = UPD ? qemb_prev + (size_t)idx_prev[wbase + lr] * DIMD : nullptr;
    float* orow = UPD ? res_out + (size_t)(wbase + lr) * DIMD : nullptr;

#define PRO(dc_) { \
    const int off = (dc_) * 32 + lg * 8; \
    float4 x0 = *reinterpret_cast<const float4*>(rrow + off); \
    float4 x1 = *reinterpret_cast<const float4*>(rrow + off + 4); \
    if (UPD) { \
        const float4 q0 = *reinterpret_cast<const float4*>(qrow + off); \
        const float4 q1 = *reinterpret_cast<const float4*>(qrow + off + 4); \
        x0.x -= q0.x; x0.y -= q0.y; x0.z -= q0.z; x0.w -= q0.w; \
        x1.x -= q1.x; x1.y -= q1.y; x1.z -= q1.z; x1.w -= q1.w; \
        lsum += x0.x * x0.x + x0.y * x0.y + x0.z * x0.z + x0.w * x0.w \
              + x1.x * x1.x + x1.y * x1.y + x1.z * x1.z + x1.w * x1.w; \
        *reinterpret_cast<float4*>(orow + off)     = x0; \
        *reinterpret_cast<float4*>(orow + off + 4) = x1; \
    } \
    af_##dc_ = cvt8_f16(x0, x1); }

    PRO(0) PRO(1) PRO(2) PRO(3) PRO(4) PRO(5) PRO(6) PRO(7)
#undef PRO

    if (UPD) {
        #pragma unroll
        for (int o = 32; o; o >>= 1) lsum += __shfl_down(lsum, o);
        if (lane == 0) atomicAdd(loss_acc, (double)lsum);
    }

    // ---- named packed-key top-3 state (one token set, 4 r-slots) ----
    unsigned k1_0 = 0xFFFFFFFFu, k2_0 = 0xFFFFFFFFu, k3_0 = 0xFFFFFFFFu;
    unsigned k1_1 = 0xFFFFFFFFu, k2_1 = 0xFFFFFFFFu, k3_1 = 0xFFFFFFFFu;
    unsigned k1_2 = 0xFFFFFFFFu, k2_2 = 0xFFFFFFFFu, k3_2 = 0xFFFFFFFFu;
    unsigned k1_3 = 0xFFFFFFFFu, k2_3 = 0xFFFFFFFFu, k3_3 = 0xFFFFFFFFu;

#define STEP(dc_, slot_) { \
    const f16x8 h0 = u2h(sb##slot_##a), h1 = u2h(sb##slot_##b); \
    a0 = MFMA16(af_##dc_, h0, a0); \
    a1 = MFMA16(af_##dc_, h1, a1); \
    const size_t fi_ = (size_t)(((p0 + p_i + (((dc_) + 4) >> 3)) & 31) * 16 \
                                + (((dc_) + 4) & 7) * 2); \
    sb##slot_##a = ib[fi_ * 64]; \
    sb##slot_##b = ib[(fi_ + 1) * 64]; }

#define LADD(k1_, k2_, k3_, sval_, cbn_) { \
    const unsigned key_ = (f2u(sval_) & 0xFFFFFFC0u) | (cbn_); \
    const unsigned nk3_ = med3u(key_, k2_, k3_); \
    const unsigned nk2_ = med3u(k1_, key_, k2_); \
    k1_ = min(k1_, key_); k2_ = nk2_; k3_ = nk3_; }

    for (int p_i = 0; p_i < 32; ++p_i) {
        const int p_eff = (p0 + p_i) & 31;
        const float wn0 = wnorml[p_eff * 32 + lr];
        const float wn1 = wnorml[p_eff * 32 + 16 + lr];

        f32x4 a0 = (f32x4)0.0f, a1 = (f32x4)0.0f;

        STEP(0, 0) STEP(1, 1) STEP(2, 2) STEP(3, 3)
        STEP(4, 0) STEP(5, 1) STEP(6, 2) STEP(7, 3)

        const unsigned cb0 = (unsigned)(p_eff * 2), cb1 = cb0 + 1;
        LADD(k1_0, k2_0, k3_0, fmaf(-2.0f, a0[0], wn0), cb0)
        LADD(k1_1, k2_1, k3_1, fmaf(-2.0f, a0[1], wn0), cb0)
        LADD(k1_2, k2_2, k3_2, fmaf(-2.0f, a0[2], wn0), cb0)
        LADD(k1_3, k2_3, k3_3, fmaf(-2.0f, a0[3], wn0), cb0)
        LADD(k1_0, k2_0, k3_0, fmaf(-2.0f, a1[0], wn1), cb1)
        LADD(k1_1, k2_1, k3_1, fmaf(-2.0f, a1[1], wn1), cb1)
        LADD(k1_2, k2_2, k3_2, fmaf(-2.0f, a1[2], wn1), cb1)
        LADD(k1_3, k2_3, k3_3, fmaf(-2.0f, a1[3], wn1), cb1)
    }
#undef STEP
#undef LADD

    // ---- gather keys; butterfly merge across the 16 lr-lanes; writeout ----
    unsigned K1[4] = {k1_0, k1_1, k1_2, k1_3};
    unsigned K2[4] = {k2_0, k2_1, k2_2, k2_3};
    unsigned K3[4] = {k3_0, k3_1, k3_2, k3_3};
    #pragma unroll
    for (int r = 0; r < 4; ++r) {
        unsigned v1 = K1[r] & 0xFFFFFFC0u;
        unsigned v2 = K2[r] & 0xFFFFFFC0u;
        unsigned v3 = K3[r] & 0xFFFFFFC0u;
        int id1 = (int)((K1[r] & 63u) << 4) | lr;
        int id2 = (int)((K2[r] & 63u) << 4) | lr;
        #pragma unroll
        for (int d = 1; d < 16; d <<= 1) {
            const unsigned o1 = __shfl_xor(v1, d);
            const unsigned o2 = __shfl_xor(v2, d);
            const unsigned o3 = __shfl_xor(v3, d);
            const int     oi1 = __shfl_xor(id1, d);
            const int     oi2 = __shfl_xor(id2, d);
            merge3u(v1, v2, v3, id1, id2, o1, o2, o3, oi1, oi2);
        }
        if (lr == 0) {
            const int gt = wbase + lg * 4 + r;
            idxl[gt] = (unsigned short)id1;
            const float s1 = u2f(v1), s2 = u2f(v2), s3 = u2f(v3);
            if (s2 - s1 < TAUP) {
                if (s3 - s1 >= TAUP) {   // exact winner must be id1 or id2
                    const int pp = atomicAdd(&cnts_l[1], 1);
                    plist[pp] = make_int2(gt, id1 | (id2 << 16));
                } else {                 // rare: full exact rescan
                    const int pp = atomicAdd(&cnts_l[0], 1);
                    flist[pp] = gt;
                }
            }
        }
    }
}

// ---- merged exact rescue: blocks [0,1024) pair-compare, [1024,1536) full ---
__global__ void k_rescue(const float* rsrc, const float* __restrict__ embl,
                         const float* __restrict__ wnorml,
                         const int2* __restrict__ plist, const int* __restrict__ flist,
                         const int* __restrict__ cnts_l,
                         unsigned short* __restrict__ idxl)
{
    __shared__ float rbuf[DIMD];
    const int lane = threadIdx.x;   // blockDim.x == 64
    if (blockIdx.x < 1024) {
        int cnt = cnts_l[1]; if (cnt > NTOK) cnt = NTOK;
        for (int k = blockIdx.x; k < cnt; k += 1024) {
            const int2 e = plist[k];
            const int t  = e.x;
            const int c1 = e.y & 0xffff, c2 = (e.y >> 16) & 0xffff;
            reinterpret_cast<float4*>(rbuf)[lane] =
                reinterpret_cast<const float4*>(rsrc + (size_t)t * DIMD)[lane];
            __syncthreads();
            const float rnv = np_pairnorm_row(rbuf, lane & 15);
            const int myc = lane ? c2 : c1;
            float acc = 0.0f;
            if (lane < 2) {
                const float* wr = embl + (size_t)myc * DIMD;
                for (int d = 0; d < DIMD; d += 4) {   // sequential fmaf, d ascending
                    const float4 wv = *reinterpret_cast<const float4*>(wr + d);
                    acc = fmaf(rbuf[d + 0], wv.x, acc);
                    acc = fmaf(rbuf[d + 1], wv.y, acc);
                    acc = fmaf(rbuf[d + 2], wv.z, acc);
                    acc = fmaf(rbuf[d + 3], wv.w, acc);
                }
            }
            const float s_l = fmaf(-2.0f, acc, rnv) + wnorml[myc];
            const float s2  = __shfl(s_l, 1);
            if (lane == 0) {
                int win;
                if (s_l < s2)      win = c1;
                else if (s2 < s_l) win = c2;
                else               win = min(c1, c2);
                idxl[t] = (unsigned short)win;
            }
            __syncthreads();
        }
    } else {
        int cnt = cnts_l[0]; if (cnt > NTOK) cnt = NTOK;
        for (int k = blockIdx.x - 1024; k < cnt; k += 512) {
            const int t = flist[k];
            reinterpret_cast<float4*>(rbuf)[lane] =
                reinterpret_cast<const float4*>(rsrc + (size_t)t * DIMD)[lane];
            __syncthreads();
            const float rnv = np_pairnorm_row(rbuf, lane & 15);
            float best = 3.0e38f; int besti = 0x7fffffff;
            for (int j = 0; j < 4; ++j) {
                const float* w0 = embl + (size_t)(j * 256 + lane) * DIMD;
                float a0 = 0.f, a1 = 0.f, a2 = 0.f, a3 = 0.f;
                for (int d = 0; d < DIMD; d += 4) {
                    const float4 r4 = *reinterpret_cast<const float4*>(&rbuf[d]);
                    const float4 v0 = *reinterpret_cast<const float4*>(w0 + d);
                    const float4 v1 = *reinterpret_cast<const float4*>(w0 + 64 * DIMD + d);
                    const float4 v2 = *reinterpret_cast<const float4*>(w0 + 128 * DIMD + d);
                    const float4 v3 = *reinterpret_cast<const float4*>(w0 + 192 * DIMD + d);
                    a0 = fmaf(r4.x, v0.x, a0); a0 = fmaf(r4.y, v0.y, a0);
                    a0 = fmaf(r4.z, v0.z, a0); a0 = fmaf(r4.w, v0.w, a0);
                    a1 = fmaf(r4.x, v1.x, a1); a1 = fmaf(r4.y, v1.y, a1);
                    a1 = fmaf(r4.z, v1.z, a1); a1 = fmaf(r4.w, v1.w, a1);
                    a2 = fmaf(r4.x, v2.x, a2); a2 = fmaf(r4.y, v2.y, a2);
                    a2 = fmaf(r4.z, v2.z, a2); a2 = fmaf(r4.w, v2.w, a2);
                    a3 = fmaf(r4.x, v3.x, a3); a3 = fmaf(r4.y, v3.y, a3);
                    a3 = fmaf(r4.z, v3.z, a3); a3 = fmaf(r4.w, v3.w, a3);
                }
                float s; int c;
                c = j * 256 + lane;        s = fmaf(-2.0f, a0, rnv) + wnorml[c];
                if (s < best) { best = s; besti = c; }
                c = j * 256 + 64 + lane;   s = fmaf(-2.0f, a1, rnv) + wnorml[c];
                if (s < best) { best = s; besti = c; }
                c = j * 256 + 128 + lane;  s = fmaf(-2.0f, a2, rnv) + wnorml[c];
                if (s < best) { best = s; besti = c; }
                c = j * 256 + 192 + lane;  s = fmaf(-2.0f, a3, rnv) + wnorml[c];
                if (s < best) { best = s; besti = c; }
            }
            #pragma unroll
            for (int off = 32; off > 0; off >>= 1) {
                const float ov = __shfl_down(best, off);
                const int   oi = __shfl_down(besti, off);
                if (ov < best || (ov == best && oi < besti)) { best = ov; besti = oi; }
            }
            if (lane == 0) idxl[t] = (unsigned short)besti;
            __syncthreads();
        }
    }
}

// ---- finale: output (exact code_sum chain) + level-3 loss ------------------
__global__ void k_finale(const float* __restrict__ latent, const float* __restrict__ emb,
                         const unsigned short* __restrict__ idx, float* outq,
                         double* loss_acc)
{
    const int gtid  = blockIdx.x * blockDim.x + threadIdx.x;
    const int gwave = gtid >> 6;
    const int lane  = threadIdx.x & 63;
    const int nwave = (gridDim.x * blockDim.x) >> 6;
    float lsum = 0.0f;
    for (int t = gwave; t < NTOK; t += nwave) {
        const float4 q0 = reinterpret_cast<const float4*>(
            emb + ((size_t)0 * VOC + idx[0 * NTOK + t]) * DIMD)[lane];
        const float4 q1 = reinterpret_cast<const float4*>(
            emb + ((size_t)1 * VOC + idx[1 * NTOK + t]) * DIMD)[lane];
        const float4 q2 = reinterpret_cast<const float4*>(
            emb + ((size_t)2 * VOC + idx[2 * NTOK + t]) * DIMD)[lane];
        const float4 q3 = reinterpret_cast<const float4*>(
            emb + ((size_t)3 * VOC + idx[3 * NTOK + t]) * DIMD)[lane];
        const float4 l4 = reinterpret_cast<const float4*>(latent + (size_t)t * DIMD)[lane];
        float4 o;
        {
            float c, r3, e;
            c = q0.x; c = c + q1.x; c = c + q2.x; c = c + q3.x; o.x = l4.x + (c - l4.x);
            r3 = l4.x - q0.x; r3 = r3 - q1.x; r3 = r3 - q2.x; e = q3.x - r3; lsum += e * e;
            c = q0.y; c = c + q1.y; c = c + q2.y; c = c + q3.y; o.y = l4.y + (c - l4.y);
            r3 = l4.y - q0.y; r3 = r3 - q1.y; r3 = r3 - q2.y; e = q3.y - r3; lsum += e * e;
            c = q0.z; c = c + q1.z; c = c + q2.z; c = c + q3.z; o.z = l4.z + (c - l4.z);
            r3 = l4.z - q0.z; r3 = r3 - q1.z; r3 = r3 - q2.z; e = q3.z - r3; lsum += e * e;
            c = q0.w; c = c + q1.w; c = c + q2.w; c = c + q3.w; o.w = l4.w + (c - l4.w);
            r3 = l4.w - q0.w; r3 = r3 - q1.w; r3 = r3 - q2.w; e = q3.w - r3; lsum += e * e;
        }
        reinterpret_cast<float4*>(outq + (size_t)t * DIMD)[lane] = o;
    }
    #pragma unroll
    for (int off = 32; off > 0; off >>= 1) lsum += __shfl_down(lsum, off);
    if (lane == 0) atomicAdd(loss_acc, (double)lsum);
}

__global__ void k_loss_final(const double* __restrict__ loss_acc, float* __restrict__ out0)
{
    *out0 = (float)(1.25 * (*loss_acc) / ((double)NTOK * (double)DIMD));
}

extern "C" void kernel_launch(void* const* d_in, const int* in_sizes, int n_in,
                              void* d_out, int out_size, void* d_ws, size_t ws_size,
                              hipStream_t stream)
{
    const float* latent = (const float*)d_in[0];
    const float* emb    = (const float*)d_in[1];
    float* out = (float*)d_out;
    float* res = out + 1;   // residual scratch; rewritten by k_finale

    char*           ws       = (char*)d_ws;
    double*         loss_acc = (double*)ws;
    int*            cnts     = (int*)(ws + 8);
    float*          wnorm    = (float*)(ws + 64);
    unsigned short* idx      = (unsigned short*)(ws + 16448);
    int*            flist    = (int*)(ws + 540736);
    int2*           plist    = (int2*)(ws + 802880);
    uint4*          wimg     = (uint4*)(ws + 1327168);

    k_wsplit<<<NLEV * 32, 256, 0, stream>>>(emb, wimg, cnts);
    k_pairnorm<<<256, 256, 0, stream>>>(emb, wnorm, NLEV * VOC, loss_acc);

    for (int l = 0; l < NLEV; ++l) {
        const float*    W    = emb + (size_t)l * VOC * DIMD;
        unsigned short* idxl = idx + l * NTOK;
        const uint4*    wl   = wimg + (size_t)l * 512 * 64;
        const float*    wnl  = wnorm + l * VOC;
        int*            cl   = cnts + 2 * l;
        if (l == 0)
            k_screen<0><<<NTOK / 64, 256, 0, stream>>>(latent, nullptr, nullptr, nullptr,
                                                       wl, wnl, idxl, plist, flist, cl, loss_acc);
        else
            k_screen<1><<<NTOK / 64, 256, 0, stream>>>((l == 1) ? latent : res,
                                                       emb + (size_t)(l - 1) * VOC * DIMD,
                                                       idx + (l - 1) * NTOK, res,
                                                       wl, wnl, idxl, plist, flist, cl, loss_acc);
        const float* rsrc_l = (l == 0) ? latent : res;
        k_rescue<<<1536, 64, 0, stream>>>(rsrc_l, W, wnl, plist, flist, cl, idxl);
    }
    k_finale<<<1024, 256, 0, stream>>>(latent, emb, idx, res, loss_acc);
    k_loss_final<<<1, 1, 0, stream>>>(loss_acc, out);
}

// Round 12
// 653.140 us; speedup vs baseline: 1.1606x; 1.1606x over previous
//
#include <hip/hip_runtime.h>

#define NTOK 65536
#define DIMD 256
#define VOC  1024
#define NLEV 4
#define TAUP 0.052f   // screened top-2 gap below this -> exact resolution

typedef __attribute__((ext_vector_type(8))) _Float16 f16x8;
typedef __attribute__((ext_vector_type(4))) float f32x4;

// ---------------------------------------------------------------------------
// ws layout:
//   [0]        double loss_acc
//   [8]        int    cnts[8]              (per level: [2l]=full, [2l+1]=pair)
//   [64]       float  wnorm[NLEV][VOC]     (16 KB)
//   [16448]    u16    idx[NLEV][NTOK]      (512 KB)
//   [540736]   int    flist[NTOK]          (256 KB)
//   [802880]   int2   plist[NTOK]          (512 KB)
//   [1327168]  uint4  wimg[NLEV*16*2048]   (2 MB)  f16 W, phase-tile order
// residual fp32 lives in d_out[1:] until k_finale rewrites it.
// wimg tile P (codes P*64..+64): 2048 uint4; slot s: frag fi=s>>6 (n=fi>>3,
// k=fi&7), lane=s&63 holds W[P*64+n*16+(lane&15)][k*32+(lane>>4)*8 ..+8] f16x8.
// ---------------------------------------------------------------------------

__device__ __forceinline__ uint4 cvt8_f16_u(const float4 x0, const float4 x1) {
    union { f16x8 h; uint4 u; } r;
    r.h[0] = (_Float16)x0.x; r.h[1] = (_Float16)x0.y;
    r.h[2] = (_Float16)x0.z; r.h[3] = (_Float16)x0.w;
    r.h[4] = (_Float16)x1.x; r.h[5] = (_Float16)x1.y;
    r.h[6] = (_Float16)x1.z; r.h[7] = (_Float16)x1.w;
    return r.u;
}

__device__ __forceinline__ f16x8 cvt8_f16(const float4 x0, const float4 x1) {
    union { f16x8 h; uint4 u; } r;
    r.h[0] = (_Float16)x0.x; r.h[1] = (_Float16)x0.y;
    r.h[2] = (_Float16)x0.z; r.h[3] = (_Float16)x0.w;
    r.h[4] = (_Float16)x1.x; r.h[5] = (_Float16)x1.y;
    r.h[6] = (_Float16)x1.z; r.h[7] = (_Float16)x1.w;
    return r.h;
}

__device__ __forceinline__ f16x8 u2h(uint4 u) {
    union { uint4 u; f16x8 h; } r; r.u = u; return r.h;
}

__device__ __forceinline__ void gl_lds16(const uint4* g, uint4* l) {
    __builtin_amdgcn_global_load_lds(
        (const __attribute__((address_space(1))) unsigned*)g,
        (__attribute__((address_space(3))) unsigned*)l, 16, 0, 0);
}

// monotone float->u32 (ascending), and inverse
__device__ __forceinline__ unsigned f2u(float s) {
    const int b = __float_as_int(s);
    return (unsigned)(b ^ ((b >> 31) | 0x80000000));
}
__device__ __forceinline__ float u2f(unsigned u) {
    const unsigned m = (u & 0x80000000u) ? 0x80000000u : 0xFFFFFFFFu;
    return __uint_as_float(u ^ m);
}
__device__ __forceinline__ unsigned med3u(unsigned a, unsigned b, unsigned c) {
    unsigned d;
    asm("v_med3_u32 %0, %1, %2, %3" : "=v"(d) : "v"(a), "v"(b), "v"(c));
    return d;
}

// merge two ascending u32 triples with (value, idx) lexicographic order
__device__ __forceinline__ void merge3u(unsigned& a1, unsigned& a2, unsigned& a3,
                                        int& ai1, int& ai2,
                                        unsigned o1, unsigned o2, unsigned o3,
                                        int oi1, int oi2)
{
    const bool sw = (o1 < a1) || (o1 == a1 && oi1 < ai1);
    const unsigned b1 = sw ? o1 : a1; const int bi1 = sw ? oi1 : ai1;
    const unsigned c1 = sw ? a1 : o1; const int ci1 = sw ? ai1 : oi1;
    const unsigned b2 = sw ? o2 : a2; const int bi2 = sw ? oi2 : ai2;
    const unsigned c2 = sw ? a2 : o2;
    const unsigned b3 = sw ? o3 : a3;
    a1 = b1; ai1 = bi1;
    if (c1 < b2 || (c1 == b2 && ci1 < bi2)) {
        a2 = c1; ai2 = ci1; a3 = min(b2, c2);
    } else {
        a2 = b2; ai2 = bi2; a3 = min(b3, c1);
    }
}

// ---------- pre-convert W into phase-tile-ordered f16 image -----------------
__global__ void k_wsplit(const float* __restrict__ emb, uint4* __restrict__ wimg,
                         int* cnts)
{
    if (blockIdx.x == 0 && threadIdx.x < 8) cnts[threadIdx.x] = 0;
    const int l = blockIdx.x >> 4, P = blockIdx.x & 15;   // grid = NLEV*16
    const int tid = threadIdx.x;
    #pragma unroll
    for (int i = 0; i < 8; ++i) {
        const int s  = tid + i * 256;        // 0..2047
        const int fi = s >> 6, ls = s & 63;
        const int n = fi >> 3, k = fi & 7;
        const int code = P * 64 + n * 16 + (ls & 15);
        const float* src = emb + ((size_t)(l * VOC + code)) * DIMD + k * 32 + (ls >> 4) * 8;
        const float4 x0 = *reinterpret_cast<const float4*>(src);
        const float4 x1 = *reinterpret_cast<const float4*>(src + 4);
        wimg[((size_t)(l * 16 + P)) * 2048 + s] = cvt8_f16_u(x0, x1);
    }
}

// ------------------- numpy pairwise sum-of-squares -------------------------
__device__ __forceinline__ float np_pairnorm_row(const float* row, int j)
{
#pragma clang fp contract(off)
    const int half = j >> 3;
    const int jj   = j & 7;
    const float* a = row + half * 128 + jj;
    float r = a[0] * a[0];
    #pragma unroll
    for (int i = 1; i < 16; ++i) {
        const float x  = a[8 * i];
        const float sq = x * x;
        r = r + sq;
    }
    r = r + __shfl_xor(r, 1);
    r = r + __shfl_xor(r, 2);
    r = r + __shfl_xor(r, 4);
    r = r + __shfl_xor(r, 8);
    return r;
}

__global__ void k_pairnorm(const float* src, float* __restrict__ dst,
                           int nrows, double* loss_acc)
{
    if (loss_acc && blockIdx.x == 0 && threadIdx.x == 0) *loss_acc = 0.0;
    const int gtid  = blockIdx.x * blockDim.x + threadIdx.x;
    const int gwave = gtid >> 6;
    const int lane  = threadIdx.x & 63;
    const int nwave = (gridDim.x * blockDim.x) >> 6;
    const int sub   = lane >> 4;
    const int j     = lane & 15;
    for (int r4 = gwave; r4 * 4 < nrows; r4 += nwave) {
        const int row = r4 * 4 + sub;
        const float v = np_pairnorm_row(src + (size_t)row * DIMD, j);
        if (j == 0) dst[row] = v;
    }
}

#define MFMA16(A, B, C) __builtin_amdgcn_mfma_f32_16x16x32_f16((A), (B), (C), 0, 0, 0)

// ------------- screen: LDS dbuf B + counted vmcnt, A in named regs ----------
// Block 128 tokens = 4 waves x 32. 16 phases over 64-code tiles.
template<int UPD>
__global__ __launch_bounds__(256, 2)
void k_screen(const float* rin, const float* __restrict__ qemb_prev,
              const unsigned short* __restrict__ idx_prev, float* res_out,
              const uint4* __restrict__ wimg_l, const float* __restrict__ wnorml,
              unsigned short* __restrict__ idxl, int2* __restrict__ plist,
              int* __restrict__ flist, int* cnts_l, double* loss_acc)
{
    __shared__ uint4 ldsB[2][2048];   // 64 KB double-buffered B tile

    const int tid = threadIdx.x, lane = tid & 63, w = tid >> 6;
    const int lr = lane & 15, lg = lane >> 4;
    const int wbase = blockIdx.x * 128 + w * 32;

#define STAGE(pp_, buf_) { \
    const uint4* src_ = wimg_l + (size_t)(pp_) * 2048; \
    _Pragma("unroll") \
    for (int i_ = 0; i_ < 8; ++i_) \
        gl_lds16(src_ + tid + i_ * 256, &ldsB[buf_][tid + i_ * 256]); }

    STAGE(0, 0)   // phase-0 staging flies during the A prologue

    // ---- A prologue: named fragments (+ fused residual update) ----
    f16x8 af0_0, af0_1, af0_2, af0_3, af0_4, af0_5, af0_6, af0_7;
    f16x8 af1_0, af1_1, af1_2, af1_3, af1_4, af1_5, af1_6, af1_7;
    float lsum = 0.0f;
    const float* rrow0 = rin + (size_t)(wbase + lr) * DIMD;
    const float* rrow1 = rin + (size_t)(wbase + 16 + lr) * DIMD;
    const float* qrow0 = UPD ? qemb_prev + (size_t)idx_prev[wbase + lr] * DIMD : nullptr;
    const float* qrow1 = UPD ? qemb_prev + (size_t)idx_prev[wbase + 16 + lr] * DIMD : nullptr;
    float* orow0 = UPD ? res_out + (size_t)(wbase + lr) * DIMD : nullptr;
    float* orow1 = UPD ? res_out + (size_t)(wbase + 16 + lr) * DIMD : nullptr;

#define PRO(m_, dc_) { \
    const int off = (dc_) * 32 + lg * 8; \
    float4 x0 = *reinterpret_cast<const float4*>(rrow##m_ + off); \
    float4 x1 = *reinterpret_cast<const float4*>(rrow##m_ + off + 4); \
    if (UPD) { \
        const float4 q0 = *reinterpret_cast<const float4*>(qrow##m_ + off); \
        const float4 q1 = *reinterpret_cast<const float4*>(qrow##m_ + off + 4); \
        x0.x -= q0.x; x0.y -= q0.y; x0.z -= q0.z; x0.w -= q0.w; \
        x1.x -= q1.x; x1.y -= q1.y; x1.z -= q1.z; x1.w -= q1.w; \
        lsum += x0.x * x0.x + x0.y * x0.y + x0.z * x0.z + x0.w * x0.w \
              + x1.x * x1.x + x1.y * x1.y + x1.z * x1.z + x1.w * x1.w; \
        *reinterpret_cast<float4*>(orow##m_ + off)     = x0; \
        *reinterpret_cast<float4*>(orow##m_ + off + 4) = x1; \
    } \
    af##m_##_##dc_ = cvt8_f16(x0, x1); }

    PRO(0, 0) PRO(0, 1) PRO(0, 2) PRO(0, 3) PRO(0, 4) PRO(0, 5) PRO(0, 6) PRO(0, 7)
    PRO(1, 0) PRO(1, 1) PRO(1, 2) PRO(1, 3) PRO(1, 4) PRO(1, 5) PRO(1, 6) PRO(1, 7)
#undef PRO

    if (UPD) {
        #pragma unroll
        for (int o = 32; o; o >>= 1) lsum += __shfl_down(lsum, o);
        if (lane == 0) atomicAdd(loss_acc, (double)lsum);
    }

    // ---- named packed-key top-3 state (8 token slots: 2m x 4r) ----
#define DECLK(m_, r_) unsigned k1_##m_##_##r_ = 0xFFFFFFFFu, \
    k2_##m_##_##r_ = 0xFFFFFFFFu, k3_##m_##_##r_ = 0xFFFFFFFFu;
    DECLK(0, 0) DECLK(0, 1) DECLK(0, 2) DECLK(0, 3)
    DECLK(1, 0) DECLK(1, 1) DECLK(1, 2) DECLK(1, 3)
#undef DECLK

    asm volatile("s_waitcnt vmcnt(0)" ::: "memory");
    __builtin_amdgcn_s_barrier();
    __builtin_amdgcn_sched_barrier(0);

#define KSTEP(k_) { \
    const f16x8 b0 = u2h(LB[((0 * 8) + k_) * 64 + lane]); \
    const f16x8 b1 = u2h(LB[((1 * 8) + k_) * 64 + lane]); \
    const f16x8 b2 = u2h(LB[((2 * 8) + k_) * 64 + lane]); \
    const f16x8 b3 = u2h(LB[((3 * 8) + k_) * 64 + lane]); \
    c00 = MFMA16(af0_##k_, b0, c00); c10 = MFMA16(af1_##k_, b0, c10); \
    c01 = MFMA16(af0_##k_, b1, c01); c11 = MFMA16(af1_##k_, b1, c11); \
    c02 = MFMA16(af0_##k_, b2, c02); c12 = MFMA16(af1_##k_, b2, c12); \
    c03 = MFMA16(af0_##k_, b3, c03); c13 = MFMA16(af1_##k_, b3, c13); }

#define LADD(k1_, k2_, k3_, sval_, cbn_) { \
    const unsigned key_ = (f2u(sval_) & 0xFFFFFFC0u) | (cbn_); \
    const unsigned nk3_ = med3u(key_, k2_, k3_); \
    const unsigned nk2_ = med3u(k1_, key_, k2_); \
    k1_ = min(k1_, key_); k2_ = nk2_; k3_ = nk3_; }

    for (int p = 0; p < 16; ++p) {
        const int cur = p & 1;
        if (p < 15) {
            STAGE(p + 1, cur ^ 1)
            asm volatile("s_waitcnt vmcnt(8)" ::: "memory");
        } else {
            asm volatile("s_waitcnt vmcnt(0)" ::: "memory");
        }
        __builtin_amdgcn_s_barrier();      // buf[cur] fully staged for all waves
        __builtin_amdgcn_sched_barrier(0);

        const uint4* LB = &ldsB[cur][0];
        f32x4 c00 = (f32x4)0.0f, c01 = (f32x4)0.0f, c02 = (f32x4)0.0f, c03 = (f32x4)0.0f;
        f32x4 c10 = (f32x4)0.0f, c11 = (f32x4)0.0f, c12 = (f32x4)0.0f, c13 = (f32x4)0.0f;

        __builtin_amdgcn_s_setprio(1);
        KSTEP(0) KSTEP(1) KSTEP(2) KSTEP(3) KSTEP(4) KSTEP(5) KSTEP(6) KSTEP(7)
        __builtin_amdgcn_s_setprio(0);

        // ladder: key low 6 bits = code>>4 = p*4 + n
        const float wn0 = wnorml[p * 64 + 0 * 16 + lr];
        const float wn1 = wnorml[p * 64 + 1 * 16 + lr];
        const float wn2 = wnorml[p * 64 + 2 * 16 + lr];
        const float wn3 = wnorml[p * 64 + 3 * 16 + lr];
        const unsigned cb = (unsigned)(p * 4);
#define LADN(m_, cx_, wn_, n_) \
        LADD(k1_##m_##_0, k2_##m_##_0, k3_##m_##_0, fmaf(-2.0f, cx_[0], wn_), cb + n_) \
        LADD(k1_##m_##_1, k2_##m_##_1, k3_##m_##_1, fmaf(-2.0f, cx_[1], wn_), cb + n_) \
        LADD(k1_##m_##_2, k2_##m_##_2, k3_##m_##_2, fmaf(-2.0f, cx_[2], wn_), cb + n_) \
        LADD(k1_##m_##_3, k2_##m_##_3, k3_##m_##_3, fmaf(-2.0f, cx_[3], wn_), cb + n_)
        LADN(0, c00, wn0, 0) LADN(0, c01, wn1, 1) LADN(0, c02, wn2, 2) LADN(0, c03, wn3, 3)
        LADN(1, c10, wn0, 0) LADN(1, c11, wn1, 1) LADN(1, c12, wn2, 2) LADN(1, c13, wn3, 3)
#undef LADN

        asm volatile("s_waitcnt lgkmcnt(0)" ::: "memory");
        __builtin_amdgcn_sched_barrier(0);
        __builtin_amdgcn_s_barrier();      // all reads of buf[cur] done; next
        __builtin_amdgcn_sched_barrier(0); // phase stages into buf[cur]
    }
#undef KSTEP
#undef LADD
#undef STAGE

    // ---- gather keys; butterfly merge across the 16 lr-lanes; writeout ----
    unsigned K1[2][4] = {{k1_0_0, k1_0_1, k1_0_2, k1_0_3},
                         {k1_1_0, k1_1_1, k1_1_2, k1_1_3}};
    unsigned K2[2][4] = {{k2_0_0, k2_0_1, k2_0_2, k2_0_3},
                         {k2_1_0, k2_1_1, k2_1_2, k2_1_3}};
    unsigned K3[2][4] = {{k3_0_0, k3_0_1, k3_0_2, k3_0_3},
                         {k3_1_0, k3_1_1, k3_1_2, k3_1_3}};
    #pragma unroll
    for (int m = 0; m < 2; ++m)
        #pragma unroll
        for (int r = 0; r < 4; ++r) {
            unsigned v1 = K1[m][r] & 0xFFFFFFC0u;
            unsigned v2 = K2[m][r] & 0xFFFFFFC0u;
            unsigned v3 = K3[m][r] & 0xFFFFFFC0u;
            int id1 = (int)((K1[m][r] & 63u) << 4) | lr;
            int id2 = (int)((K2[m][r] & 63u) << 4) | lr;
            #pragma unroll
            for (int d = 1; d < 16; d <<= 1) {
                const unsigned o1 = __shfl_xor(v1, d);
                const unsigned o2 = __shfl_xor(v2, d);
                const unsigned o3 = __shfl_xor(v3, d);
                const int     oi1 = __shfl_xor(id1, d);
                const int     oi2 = __shfl_xor(id2, d);
                merge3u(v1, v2, v3, id1, id2, o1, o2, o3, oi1, oi2);
            }
            if (lr == 0) {
                const int gt = wbase + m * 16 + lg * 4 + r;
                idxl[gt] = (unsigned short)id1;
                const float s1 = u2f(v1), s2 = u2f(v2), s3 = u2f(v3);
                if (s2 - s1 < TAUP) {
                    if (s3 - s1 >= TAUP) {   // exact winner must be id1 or id2
                        const int pp = atomicAdd(&cnts_l[1], 1);
                        plist[pp] = make_int2(gt, id1 | (id2 << 16));
                    } else {                 // rare: full exact rescan
                        const int pp = atomicAdd(&cnts_l[0], 1);
                        flist[pp] = gt;
                    }
                }
            }
        }
}

// ---- merged exact rescue: blocks [0,1024) pair-compare, [1024,1536) full ---
__global__ void k_rescue(const float* rsrc, const float* __restrict__ embl,
                         const float* __restrict__ wnorml,
                         const int2* __restrict__ plist, const int* __restrict__ flist,
                         const int* __restrict__ cnts_l,
                         unsigned short* __restrict__ idxl)
{
    __shared__ float rbuf[DIMD];
    const int lane = threadIdx.x;   // blockDim.x == 64
    if (blockIdx.x < 1024) {
        int cnt = cnts_l[1]; if (cnt > NTOK) cnt = NTOK;
        for (int k = blockIdx.x; k < cnt; k += 1024) {
            const int2 e = plist[k];
            const int t  = e.x;
            const int c1 = e.y & 0xffff, c2 = (e.y >> 16) & 0xffff;
            reinterpret_cast<float4*>(rbuf)[lane] =
                reinterpret_cast<const float4*>(rsrc + (size_t)t * DIMD)[lane];
            __syncthreads();
            const float rnv = np_pairnorm_row(rbuf, lane & 15);
            const int myc = lane ? c2 : c1;
            float acc = 0.0f;
            if (lane < 2) {
                const float* wr = embl + (size_t)myc * DIMD;
                for (int d = 0; d < DIMD; d += 4) {   // sequential fmaf, d ascending
                    const float4 wv = *reinterpret_cast<const float4*>(wr + d);
                    acc = fmaf(rbuf[d + 0], wv.x, acc);
                    acc = fmaf(rbuf[d + 1], wv.y, acc);
                    acc = fmaf(rbuf[d + 2], wv.z, acc);
                    acc = fmaf(rbuf[d + 3], wv.w, acc);
                }
            }
            const float s_l = fmaf(-2.0f, acc, rnv) + wnorml[myc];
            const float s2  = __shfl(s_l, 1);
            if (lane == 0) {
                int win;
                if (s_l < s2)      win = c1;
                else if (s2 < s_l) win = c2;
                else               win = min(c1, c2);
                idxl[t] = (unsigned short)win;
            }
            __syncthreads();
        }
    } else {
        int cnt = cnts_l[0]; if (cnt > NTOK) cnt = NTOK;
        for (int k = blockIdx.x - 1024; k < cnt; k += 512) {
            const int t = flist[k];
            reinterpret_cast<float4*>(rbuf)[lane] =
                reinterpret_cast<const float4*>(rsrc + (size_t)t * DIMD)[lane];
            __syncthreads();
            const float rnv = np_pairnorm_row(rbuf, lane & 15);
            float best = 3.0e38f; int besti = 0x7fffffff;
            for (int j = 0; j < 4; ++j) {
                const float* w0 = embl + (size_t)(j * 256 + lane) * DIMD;
                float a0 = 0.f, a1 = 0.f, a2 = 0.f, a3 = 0.f;
                for (int d = 0; d < DIMD; d += 4) {
                    const float4 r4 = *reinterpret_cast<const float4*>(&rbuf[d]);
                    const float4 v0 = *reinterpret_cast<const float4*>(w0 + d);
                    const float4 v1 = *reinterpret_cast<const float4*>(w0 + 64 * DIMD + d);
                    const float4 v2 = *reinterpret_cast<const float4*>(w0 + 128 * DIMD + d);
                    const float4 v3 = *reinterpret_cast<const float4*>(w0 + 192 * DIMD + d);
                    a0 = fmaf(r4.x, v0.x, a0); a0 = fmaf(r4.y, v0.y, a0);
                    a0 = fmaf(r4.z, v0.z, a0); a0 = fmaf(r4.w, v0.w, a0);
                    a1 = fmaf(r4.x, v1.x, a1); a1 = fmaf(r4.y, v1.y, a1);
                    a1 = fmaf(r4.z, v1.z, a1); a1 = fmaf(r4.w, v1.w, a1);
                    a2 = fmaf(r4.x, v2.x, a2); a2 = fmaf(r4.y, v2.y, a2);
                    a2 = fmaf(r4.z, v2.z, a2); a2 = fmaf(r4.w, v2.w, a2);
                    a3 = fmaf(r4.x, v3.x, a3); a3 = fmaf(r4.y, v3.y, a3);
                    a3 = fmaf(r4.z, v3.z, a3); a3 = fmaf(r4.w, v3.w, a3);
                }
                float s; int c;
                c = j * 256 + lane;        s = fmaf(-2.0f, a0, rnv) + wnorml[c];
                if (s < best) { best = s; besti = c; }
                c = j * 256 + 64 + lane;   s = fmaf(-2.0f, a1, rnv) + wnorml[c];
                if (s < best) { best = s; besti = c; }
                c = j * 256 + 128 + lane;  s = fmaf(-2.0f, a2, rnv) + wnorml[c];
                if (s < best) { best = s; besti = c; }
                c = j * 256 + 192 + lane;  s = fmaf(-2.0f, a3, rnv) + wnorml[c];
                if (s < best) { best = s; besti = c; }
            }
            #pragma unroll
            for (int off = 32; off > 0; off >>= 1) {
                const float ov = __shfl_down(best, off);
                const int   oi = __shfl_down(besti, off);
                if (ov < best || (ov == best && oi < besti)) { best = ov; besti = oi; }
            }
            if (lane == 0) idxl[t] = (unsigned short)besti;
            __syncthreads();
        }
    }
}

// ---- finale: output (exact code_sum chain) + level-3 loss ------------------
__global__ void k_finale(const float* __restrict__ latent, const float* __restrict__ emb,
                         const unsigned short* __restrict__ idx, float* outq,
                         double* loss_acc)
{
    const int gtid  = blockIdx.x * blockDim.x + threadIdx.x;
    const int gwave = gtid >> 6;
    const int lane  = threadIdx.x & 63;
    const int nwave = (gridDim.x * blockDim.x) >> 6;
    float lsum = 0.0f;
    for (int t = gwave; t < NTOK; t += nwave) {
        const float4 q0 = reinterpret_cast<const float4*>(
            emb + ((size_t)0 * VOC + idx[0 * NTOK + t]) * DIMD)[lane];
        const float4 q1 = reinterpret_cast<const float4*>(
            emb + ((size_t)1 * VOC + idx[1 * NTOK + t]) * DIMD)[lane];
        const float4 q2 = reinterpret_cast<const float4*>(
            emb + ((size_t)2 * VOC + idx[2 * NTOK + t]) * DIMD)[lane];
        const float4 q3 = reinterpret_cast<const float4*>(
            emb + ((size_t)3 * VOC + idx[3 * NTOK + t]) * DIMD)[lane];
        const float4 l4 = reinterpret_cast<const float4*>(latent + (size_t)t * DIMD)[lane];
        float4 o;
        {
            float c, r3, e;
            c = q0.x; c = c + q1.x; c = c + q2.x; c = c + q3.x; o.x = l4.x + (c - l4.x);
            r3 = l4.x - q0.x; r3 = r3 - q1.x; r3 = r3 - q2.x; e = q3.x - r3; lsum += e * e;
            c = q0.y; c = c + q1.y; c = c + q2.y; c = c + q3.y; o.y = l4.y + (c - l4.y);
            r3 = l4.y - q0.y; r3 = r3 - q1.y; r3 = r3 - q2.y; e = q3.y - r3; lsum += e * e;
            c = q0.z; c = c + q1.z; c = c + q2.z; c = c + q3.z; o.z = l4.z + (c - l4.z);
            r3 = l4.z - q0.z; r3 = r3 - q1.z; r3 = r3 - q2.z; e = q3.z - r3; lsum += e * e;
            c = q0.w; c = c + q1.w; c = c + q2.w; c = c + q3.w; o.w = l4.w + (c - l4.w);
            r3 = l4.w - q0.w; r3 = r3 - q1.w; r3 = r3 - q2.w; e = q3.w - r3; lsum += e * e;
        }
        reinterpret_cast<float4*>(outq + (size_t)t * DIMD)[lane] = o;
    }
    #pragma unroll
    for (int off = 32; off > 0; off >>= 1) lsum += __shfl_down(lsum, off);
    if (lane == 0) atomicAdd(loss_acc, (double)lsum);
}

__global__ void k_loss_final(const double* __restrict__ loss_acc, float* __restrict__ out0)
{
    *out0 = (float)(1.25 * (*loss_acc) / ((double)NTOK * (double)DIMD));
}

extern "C" void kernel_launch(void* const* d_in, const int* in_sizes, int n_in,
                              void* d_out, int out_size, void* d_ws, size_t ws_size,
                              hipStream_t stream)
{
    const float* latent = (const float*)d_in[0];
    const float* emb    = (const float*)d_in[1];
    float* out = (float*)d_out;
    float* res = out + 1;   // residual scratch; rewritten by k_finale

    char*           ws       = (char*)d_ws;
    double*         loss_acc = (double*)ws;
    int*            cnts     = (int*)(ws + 8);
    float*          wnorm    = (float*)(ws + 64);
    unsigned short* idx      = (unsigned short*)(ws + 16448);
    int*            flist    = (int*)(ws + 540736);
    int2*           plist    = (int2*)(ws + 802880);
    uint4*          wimg     = (uint4*)(ws + 1327168);

    k_wsplit<<<NLEV * 16, 256, 0, stream>>>(emb, wimg, cnts);
    k_pairnorm<<<256, 256, 0, stream>>>(emb, wnorm, NLEV * VOC, loss_acc);

    for (int l = 0; l < NLEV; ++l) {
        const float*    W    = emb + (size_t)l * VOC * DIMD;
        unsigned short* idxl = idx + l * NTOK;
        const uint4*    wl   = wimg + (size_t)l * 16 * 2048;
        const float*    wnl  = wnorm + l * VOC;
        int*            cl   = cnts + 2 * l;
        if (l == 0)
            k_screen<0><<<NTOK / 128, 256, 0, stream>>>(latent, nullptr, nullptr, nullptr,
                                                        wl, wnl, idxl, plist, flist, cl, loss_acc);
        else
            k_screen<1><<<NTOK / 128, 256, 0, stream>>>((l == 1) ? latent : res,
                                                        emb + (size_t)(l - 1) * VOC * DIMD,
                                                        idx + (l - 1) * NTOK, res,
                                                        wl, wnl, idxl, plist, flist, cl, loss_acc);
        const float* rsrc_l = (l == 0) ? latent : res;
        k_rescue<<<1536, 64, 0, stream>>>(rsrc_l, W, wnl, plist, flist, cl, idxl);
    }
    k_finale<<<1024, 256, 0, stream>>>(latent, emb, idx, res, loss_acc);
    k_loss_final<<<1, 1, 0, stream>>>(loss_acc, out);
}